// Round 1
// baseline (144.210 us; speedup 1.0000x reference)
//
#include <hip/hip_runtime.h>
#include <math.h>

// Problem sizes (fixed by setup_inputs): S=2, B=1024, D=128, H=512, CTX=128
constexpr int S_  = 2;
constexpr int B_  = 1024;
constexpr int D_  = 128;
constexpr int H_  = 512;
constexpr int CTX_ = 128;

// ---------------------------------------------------------------------------
// Prep kernel 1: ctx_term[b,h] = sum_c context[b,c] * Wc[h,c] + b1[h]
// grid = B_, block = H_ (one thread per h)
// ---------------------------------------------------------------------------
__global__ __launch_bounds__(H_) void ctx_kernel(
    const float* __restrict__ context, const float* __restrict__ Wc,
    const float* __restrict__ b1, float* __restrict__ ctx_term)
{
    __shared__ float crow[CTX_];
    const int b = blockIdx.x;
    const int h = threadIdx.x;
    if (h < CTX_) crow[h] = context[(size_t)b * CTX_ + h];
    __syncthreads();
    const float* wr = Wc + (size_t)h * CTX_;
    float acc = b1[h];
#pragma unroll
    for (int c = 0; c < CTX_; c += 4) {
        float4 w = *reinterpret_cast<const float4*>(wr + c);
        acc = fmaf(w.x, crow[c + 0], acc);
        acc = fmaf(w.y, crow[c + 1], acc);
        acc = fmaf(w.z, crow[c + 2], acc);
        acc = fmaf(w.w, crow[c + 3], acc);
    }
    ctx_term[(size_t)b * H_ + h] = acc;
}

// ---------------------------------------------------------------------------
// Prep kernel 2: W1T[d,h] = W1[h,d]   (unmasked; mask applied on the fly)
// ---------------------------------------------------------------------------
__global__ __launch_bounds__(256) void w1t_kernel(
    const float* __restrict__ W1, float* __restrict__ W1T)
{
    int t = blockIdx.x * 256 + threadIdx.x;
    if (t >= D_ * H_) return;
    int d = t / H_;
    int h = t - d * H_;
    W1T[t] = W1[(size_t)h * D_ + d];
}

// ---------------------------------------------------------------------------
// Main kernel: one 64-lane wave per (s,b) chain. Each lane owns 8 hidden
// units h = lane*8 + j. Per step d:
//   r[j]   = (mh[j] <= d) ? relu(a[j]) : 0        (MADE output mask M2)
//   mu     = reduce64( sum_j W2[d,   h_j] * r[j] ) + b2[d]
//   ps     = reduce64( sum_j W2[d+D, h_j] * r[j] ) + b2[d+D]
//   z_d    = mu + softplus(ps) * eps[s,b,d]
//   a[j]  += (mh[j] > d) ? W1[h_j,d] * z_d : 0    (MADE input mask M1)
// ---------------------------------------------------------------------------
template <bool WS>
__global__ __launch_bounds__(256) void ar_kernel(
    const float* __restrict__ eps,
    const float* __restrict__ W2,
    const float* __restrict__ b2,
    const float* __restrict__ ctx_term,  // WS path: (B,H)
    const float* __restrict__ W1T,       // WS path: (D,H)
    const float* __restrict__ context,   // fallback path
    const float* __restrict__ Wc,        // fallback path
    const float* __restrict__ b1,        // fallback path
    const float* __restrict__ W1,        // fallback path (H,D)
    float* __restrict__ out)
{
    const int wave = (int)((blockIdx.x * blockDim.x + threadIdx.x) >> 6);
    const int lane = (int)(threadIdx.x & 63);
    if (wave >= S_ * B_) return;
    const int b  = wave % B_;
    const int hb = lane * 8;

    int mh[8];
#pragma unroll
    for (int j = 0; j < 8; ++j) mh[j] = ((hb + j) % (D_ - 1)) + 1;

    float a[8];
    if (WS) {
        float4 c0 = *reinterpret_cast<const float4*>(ctx_term + (size_t)b * H_ + hb);
        float4 c1 = *reinterpret_cast<const float4*>(ctx_term + (size_t)b * H_ + hb + 4);
        a[0] = c0.x; a[1] = c0.y; a[2] = c0.z; a[3] = c0.w;
        a[4] = c1.x; a[5] = c1.y; a[6] = c1.z; a[7] = c1.w;
    } else {
#pragma unroll
        for (int j = 0; j < 8; ++j) a[j] = b1[hb + j];
        for (int c = 0; c < CTX_; ++c) {
            float cv = context[(size_t)b * CTX_ + c];
#pragma unroll
            for (int j = 0; j < 8; ++j)
                a[j] = fmaf(Wc[(size_t)(hb + j) * CTX_ + c], cv, a[j]);
        }
    }

    const float* epsrow = eps + (size_t)wave * D_;
    float* outrow = out + (size_t)wave * D_;
    float zr0 = 0.f, zr1 = 0.f;

    auto step = [&](int d, float& zr, int match) {
        // --- loads (addresses independent of the recurrence -> prefetchable)
        const float* w2mu = W2 + (size_t)d * H_ + hb;
        const float* w2ps = W2 + (size_t)(d + D_) * H_ + hb;
        float4 m0 = *reinterpret_cast<const float4*>(w2mu);
        float4 m1 = *reinterpret_cast<const float4*>(w2mu + 4);
        float4 p0 = *reinterpret_cast<const float4*>(w2ps);
        float4 p1 = *reinterpret_cast<const float4*>(w2ps + 4);
        float wmu[8] = {m0.x, m0.y, m0.z, m0.w, m1.x, m1.y, m1.z, m1.w};
        float wps[8] = {p0.x, p0.y, p0.z, p0.w, p1.x, p1.y, p1.z, p1.w};
        float w1v[8];
        if (WS) {
            float4 u0 = *reinterpret_cast<const float4*>(W1T + (size_t)d * H_ + hb);
            float4 u1 = *reinterpret_cast<const float4*>(W1T + (size_t)d * H_ + hb + 4);
            w1v[0] = u0.x; w1v[1] = u0.y; w1v[2] = u0.z; w1v[3] = u0.w;
            w1v[4] = u1.x; w1v[5] = u1.y; w1v[6] = u1.z; w1v[7] = u1.w;
        } else {
#pragma unroll
            for (int j = 0; j < 8; ++j) w1v[j] = W1[(size_t)(hb + j) * D_ + d];
        }
        float eps_d = epsrow[d];

        // --- masked partial dot products
        float mu = 0.f, ps = 0.f;
#pragma unroll
        for (int j = 0; j < 8; ++j) {
            float r = fmaxf(a[j], 0.f);
            r = (mh[j] <= d) ? r : 0.f;
            mu = fmaf(wmu[j], r, mu);
            ps = fmaf(wps[j], r, ps);
        }

        // --- 64-lane butterfly reduce (both sums interleaved)
#pragma unroll
        for (int m = 32; m >= 1; m >>= 1) {
            mu += __shfl_xor(mu, m, 64);
            ps += __shfl_xor(ps, m, 64);
        }
        mu += b2[d];
        ps += b2[d + D_];

        // --- stable softplus + reparameterized sample
        float sp = fmaxf(ps, 0.f) + log1pf(expf(-fabsf(ps)));
        float z  = fmaf(sp, eps_d, mu);

        // --- rank-1 update of hidden pre-activations (input mask M1)
#pragma unroll
        for (int j = 0; j < 8; ++j) {
            float w = (mh[j] <= d) ? 0.f : w1v[j];
            a[j] = fmaf(w, z, a[j]);
        }
        if (lane == match) zr = z;
    };

    for (int d = 0; d < 64; ++d)   step(d, zr0, d);
    for (int d = 64; d < 128; ++d) step(d, zr1, d - 64);

    outrow[lane]      = zr0;
    outrow[lane + 64] = zr1;
}

// ---------------------------------------------------------------------------
extern "C" void kernel_launch(void* const* d_in, const int* in_sizes, int n_in,
                              void* d_out, int out_size, void* d_ws, size_t ws_size,
                              hipStream_t stream)
{
    const float* context = (const float*)d_in[0];  // (B, CTX)
    const float* eps     = (const float*)d_in[1];  // (S, B, D)
    const float* W1      = (const float*)d_in[2];  // (H, D)
    const float* Wc      = (const float*)d_in[3];  // (H, CTX)
    const float* b1      = (const float*)d_in[4];  // (H,)
    const float* W2      = (const float*)d_in[5];  // (2D, H)
    const float* b2      = (const float*)d_in[6];  // (2D,)
    float* out = (float*)d_out;

    const size_t need = (size_t)(B_ * H_ + D_ * H_) * sizeof(float);
    const int nwaves = S_ * B_;                 // 2048 chains
    const int block = 256;                      // 4 waves / block
    const int grid  = (nwaves * 64) / block;    // 512 blocks

    if (ws_size >= need) {
        float* ctx_term = (float*)d_ws;
        float* W1T      = ctx_term + (size_t)B_ * H_;
        ctx_kernel<<<B_, H_, 0, stream>>>(context, Wc, b1, ctx_term);
        w1t_kernel<<<(D_ * H_ + 255) / 256, 256, 0, stream>>>(W1, W1T);
        ar_kernel<true><<<grid, block, 0, stream>>>(
            eps, W2, b2, ctx_term, W1T, nullptr, nullptr, nullptr, nullptr, out);
    } else {
        ar_kernel<false><<<grid, block, 0, stream>>>(
            eps, W2, b2, nullptr, nullptr, context, Wc, b1, W1, out);
    }
}

// Round 2
// 102.098 us; speedup vs baseline: 1.4125x; 1.4125x over previous
//
#include <hip/hip_runtime.h>
#include <math.h>

// Problem sizes (fixed by setup_inputs): S=2, B=1024, D=128, H=512, CTX=128
constexpr int S_   = 2;
constexpr int B_   = 1024;
constexpr int D_   = 128;
constexpr int H_   = 512;
constexpr int CTX_ = 128;

// ---------------------------------------------------------------------------
// Prep 1: ctx_term[b,h] = sum_c context[b,c] * Wc[h,c] + b1[h]
// ---------------------------------------------------------------------------
__global__ __launch_bounds__(H_) void ctx_kernel(
    const float* __restrict__ context, const float* __restrict__ Wc,
    const float* __restrict__ b1, float* __restrict__ ctx_term)
{
    __shared__ float crow[CTX_];
    const int b = blockIdx.x;
    const int h = threadIdx.x;
    if (h < CTX_) crow[h] = context[(size_t)b * CTX_ + h];
    __syncthreads();
    const float* wr = Wc + (size_t)h * CTX_;
    float acc = b1[h];
#pragma unroll
    for (int c = 0; c < CTX_; c += 4) {
        float4 w = *reinterpret_cast<const float4*>(wr + c);
        acc = fmaf(w.x, crow[c + 0], acc);
        acc = fmaf(w.y, crow[c + 1], acc);
        acc = fmaf(w.z, crow[c + 2], acc);
        acc = fmaf(w.w, crow[c + 3], acc);
    }
    ctx_term[(size_t)b * H_ + h] = acc;
}

// ---------------------------------------------------------------------------
// Prep 2: combined packed weight rows. For output step d (0-indexed), unit h:
//   active (mh<=d):  WC[d][h] = (W2[d][h], W2[d+D][h])   -- readout weights
//   pending (mh> d): WC[d][h] = (W1[h][d], 0)            -- update weight
// (masks are complementary: a unit is read out iff active, updated iff pending)
// ---------------------------------------------------------------------------
__global__ __launch_bounds__(256) void pack_kernel(
    const float* __restrict__ W1, const float* __restrict__ W2,
    float2* __restrict__ WC)
{
    int t = blockIdx.x * 256 + threadIdx.x;
    if (t >= D_ * H_) return;
    int d = t >> 9;          // /H_
    int h = t & (H_ - 1);
    int mh = (h % (D_ - 1)) + 1;
    float2 v;
    if (mh <= d) { v.x = W2[(size_t)d * H_ + h]; v.y = W2[(size_t)(d + D_) * H_ + h]; }
    else         { v.x = W1[(size_t)h * D_ + d]; v.y = 0.f; }
    WC[t] = v;
}

// ---------------------------------------------------------------------------
// DPP 64-lane sum reduce (~10x lower latency than ds-routed __shfl_xor chain)
// row_shr 1/2/4/8 -> lane15/31/47/63 hold row sums; bcast15 + bcast31 combine;
// readlane(63) broadcasts via SGPR.
// ---------------------------------------------------------------------------
template <int CTRL>
__device__ __forceinline__ float dpp_add(float x)
{
    int r = __builtin_amdgcn_update_dpp(0, __float_as_int(x), CTRL, 0xF, 0xF, true);
    return x + __int_as_float(r);
}
__device__ __forceinline__ float reduce64(float x)
{
    x = dpp_add<0x111>(x);   // row_shr:1
    x = dpp_add<0x112>(x);   // row_shr:2
    x = dpp_add<0x114>(x);   // row_shr:4
    x = dpp_add<0x118>(x);   // row_shr:8
    x = dpp_add<0x142>(x);   // row_bcast:15
    x = dpp_add<0x143>(x);   // row_bcast:31
    return __int_as_float(__builtin_amdgcn_readlane(__float_as_int(x), 63));
}

__device__ __forceinline__ float softplus_fast(float x)
{
    return fmaxf(x, 0.f) + __logf(1.f + __expf(-fabsf(x)));
}

// ---------------------------------------------------------------------------
// Main: one wave runs TWO chains (they share the per-step weight row -> halves
// L2 traffic and amortizes loads/addressing). Lane owns h = lane*8..lane*8+7.
// Double-buffered prefetch of next step's weight row + scalars.
// ---------------------------------------------------------------------------
__global__ __launch_bounds__(256) void ar2_kernel(
    const float* __restrict__ eps, const float2* __restrict__ WC,
    const float* __restrict__ b2, const float* __restrict__ ctx_term,
    float* __restrict__ out)
{
    const int wv   = (int)((blockIdx.x * blockDim.x + threadIdx.x) >> 6);
    const int lane = (int)(threadIdx.x & 63);
    if (wv >= (S_ * B_) / 2) return;
    const int c0 = wv * 2, c1 = c0 + 1;        // two chain ids
    const int b0 = c0 & (B_ - 1), b1i = c1 & (B_ - 1);
    const int hb = lane * 8;

    int mh[8];
#pragma unroll
    for (int j = 0; j < 8; ++j) mh[j] = ((hb + j) % (D_ - 1)) + 1;

    float a0[8], a1[8];
    {
        float4 q0 = *reinterpret_cast<const float4*>(ctx_term + (size_t)b0 * H_ + hb);
        float4 q1 = *reinterpret_cast<const float4*>(ctx_term + (size_t)b0 * H_ + hb + 4);
        a0[0]=q0.x; a0[1]=q0.y; a0[2]=q0.z; a0[3]=q0.w;
        a0[4]=q1.x; a0[5]=q1.y; a0[6]=q1.z; a0[7]=q1.w;
        float4 r0 = *reinterpret_cast<const float4*>(ctx_term + (size_t)b1i * H_ + hb);
        float4 r1 = *reinterpret_cast<const float4*>(ctx_term + (size_t)b1i * H_ + hb + 4);
        a1[0]=r0.x; a1[1]=r0.y; a1[2]=r0.z; a1[3]=r0.w;
        a1[4]=r1.x; a1[5]=r1.y; a1[6]=r1.z; a1[7]=r1.w;
    }

    const float* e0 = eps + (size_t)c0 * D_;
    const float* e1 = eps + (size_t)c1 * D_;
    const float4* wcbase = reinterpret_cast<const float4*>(WC);

    float wA[16], wB[16];
    float e0A, e1A, bmA, bpA, e0B, e1B, bmB, bpB;

    // prologue: load step-0 row + scalars into A
    {
        const float4* p = wcbase + (size_t)0 * (H_ / 2) + lane * 4;
        float4 n0 = p[0], n1 = p[1], n2 = p[2], n3 = p[3];
        wA[0]=n0.x; wA[1]=n0.y; wA[2]=n0.z; wA[3]=n0.w;
        wA[4]=n1.x; wA[5]=n1.y; wA[6]=n1.z; wA[7]=n1.w;
        wA[8]=n2.x; wA[9]=n2.y; wA[10]=n2.z; wA[11]=n2.w;
        wA[12]=n3.x; wA[13]=n3.y; wA[14]=n3.z; wA[15]=n3.w;
        e0A = e0[0]; e1A = e1[0]; bmA = b2[0]; bpA = b2[D_];
    }

    float z00 = 0.f, z01 = 0.f, z10 = 0.f, z11 = 0.f;  // kept z: chain{0,1} x {d<64, d>=64}

    auto stepf = [&](int d, float (&wc)[16], float (&wn)[16],
                     float e0v, float e1v, float bmv, float bpv,
                     float& e0n, float& e1n, float& bmn, float& bpn) {
        int dn = d + 1; if (dn > D_ - 1) dn = D_ - 1;
        // --- prefetch next step (independent of the recurrence)
        const float4* p = wcbase + (size_t)dn * (H_ / 2) + lane * 4;
        float4 n0 = p[0], n1 = p[1], n2 = p[2], n3 = p[3];
        float en0 = e0[dn], en1 = e1[dn], bmn_ = b2[dn], bpn_ = b2[dn + D_];

        // --- masked partial dots for both chains (shared weights)
        float mu0 = 0.f, ps0 = 0.f, mu1 = 0.f, ps1 = 0.f;
#pragma unroll
        for (int j = 0; j < 8; ++j) {
            bool act = (mh[j] <= d);
            float r0 = act ? fmaxf(a0[j], 0.f) : 0.f;
            float r1 = act ? fmaxf(a1[j], 0.f) : 0.f;
            float wx = wc[2 * j], wy = wc[2 * j + 1];
            mu0 = fmaf(wx, r0, mu0); ps0 = fmaf(wy, r0, ps0);
            mu1 = fmaf(wx, r1, mu1); ps1 = fmaf(wy, r1, ps1);
        }
        // --- DPP reduces (4 independent chains interleave)
        mu0 = reduce64(mu0) + bmv;
        ps0 = reduce64(ps0) + bpv;
        mu1 = reduce64(mu1) + bmv;
        ps1 = reduce64(ps1) + bpv;

        float z0 = fmaf(softplus_fast(ps0), e0v, mu0);
        float z1 = fmaf(softplus_fast(ps1), e1v, mu1);

        // --- rank-1 update of pending units (wc.x holds W1 when pending)
#pragma unroll
        for (int j = 0; j < 8; ++j) {
            bool act = (mh[j] <= d);
            float w1e = act ? 0.f : wc[2 * j];
            a0[j] = fmaf(w1e, z0, a0[j]);
            a1[j] = fmaf(w1e, z1, a1[j]);
        }
        // --- record this step's z on its owner lane
        bool mine = (lane == (d & 63));
        if (d < 64) { z00 = mine ? z0 : z00; z10 = mine ? z1 : z10; }
        else        { z01 = mine ? z0 : z01; z11 = mine ? z1 : z11; }

        // --- commit prefetch
        wn[0]=n0.x; wn[1]=n0.y; wn[2]=n0.z; wn[3]=n0.w;
        wn[4]=n1.x; wn[5]=n1.y; wn[6]=n1.z; wn[7]=n1.w;
        wn[8]=n2.x; wn[9]=n2.y; wn[10]=n2.z; wn[11]=n2.w;
        wn[12]=n3.x; wn[13]=n3.y; wn[14]=n3.z; wn[15]=n3.w;
        e0n = en0; e1n = en1; bmn = bmn_; bpn = bpn_;
    };

    for (int d = 0; d < D_; d += 2) {
        stepf(d,     wA, wB, e0A, e1A, bmA, bpA, e0B, e1B, bmB, bpB);
        stepf(d + 1, wB, wA, e0B, e1B, bmB, bpB, e0A, e1A, bmA, bpA);
    }

    out[(size_t)c0 * D_ + lane]      = z00;
    out[(size_t)c0 * D_ + 64 + lane] = z01;
    out[(size_t)c1 * D_ + lane]      = z10;
    out[(size_t)c1 * D_ + 64 + lane] = z11;
}

// ---------------------------------------------------------------------------
// Fallback (ws too small): round-0 proven kernel, 1 chain/wave, no packing.
// ---------------------------------------------------------------------------
__global__ __launch_bounds__(256) void ar_fallback_kernel(
    const float* __restrict__ eps,
    const float* __restrict__ W2,
    const float* __restrict__ b2,
    const float* __restrict__ context,
    const float* __restrict__ Wc,
    const float* __restrict__ b1,
    const float* __restrict__ W1,
    float* __restrict__ out)
{
    const int wave = (int)((blockIdx.x * blockDim.x + threadIdx.x) >> 6);
    const int lane = (int)(threadIdx.x & 63);
    if (wave >= S_ * B_) return;
    const int b  = wave % B_;
    const int hb = lane * 8;

    int mh[8];
#pragma unroll
    for (int j = 0; j < 8; ++j) mh[j] = ((hb + j) % (D_ - 1)) + 1;

    float a[8];
#pragma unroll
    for (int j = 0; j < 8; ++j) a[j] = b1[hb + j];
    for (int c = 0; c < CTX_; ++c) {
        float cv = context[(size_t)b * CTX_ + c];
#pragma unroll
        for (int j = 0; j < 8; ++j)
            a[j] = fmaf(Wc[(size_t)(hb + j) * CTX_ + c], cv, a[j]);
    }

    const float* epsrow = eps + (size_t)wave * D_;
    float* outrow = out + (size_t)wave * D_;
    float zr0 = 0.f, zr1 = 0.f;

    for (int d = 0; d < D_; ++d) {
        const float* w2mu = W2 + (size_t)d * H_ + hb;
        const float* w2ps = W2 + (size_t)(d + D_) * H_ + hb;
        float4 m0 = *reinterpret_cast<const float4*>(w2mu);
        float4 m1 = *reinterpret_cast<const float4*>(w2mu + 4);
        float4 p0 = *reinterpret_cast<const float4*>(w2ps);
        float4 p1 = *reinterpret_cast<const float4*>(w2ps + 4);
        float wmu[8] = {m0.x, m0.y, m0.z, m0.w, m1.x, m1.y, m1.z, m1.w};
        float wps[8] = {p0.x, p0.y, p0.z, p0.w, p1.x, p1.y, p1.z, p1.w};
        float w1v[8];
#pragma unroll
        for (int j = 0; j < 8; ++j) w1v[j] = W1[(size_t)(hb + j) * D_ + d];
        float eps_d = epsrow[d];

        float mu = 0.f, ps = 0.f;
#pragma unroll
        for (int j = 0; j < 8; ++j) {
            float r = fmaxf(a[j], 0.f);
            r = (mh[j] <= d) ? r : 0.f;
            mu = fmaf(wmu[j], r, mu);
            ps = fmaf(wps[j], r, ps);
        }
        mu = reduce64(mu) + b2[d];
        ps = reduce64(ps) + b2[d + D_];

        float z = fmaf(softplus_fast(ps), eps_d, mu);
#pragma unroll
        for (int j = 0; j < 8; ++j) {
            float w = (mh[j] <= d) ? 0.f : w1v[j];
            a[j] = fmaf(w, z, a[j]);
        }
        bool mine = (lane == (d & 63));
        if (d < 64) zr0 = mine ? z : zr0; else zr1 = mine ? z : zr1;
    }

    outrow[lane]      = zr0;
    outrow[lane + 64] = zr1;
}

// ---------------------------------------------------------------------------
extern "C" void kernel_launch(void* const* d_in, const int* in_sizes, int n_in,
                              void* d_out, int out_size, void* d_ws, size_t ws_size,
                              hipStream_t stream)
{
    const float* context = (const float*)d_in[0];  // (B, CTX)
    const float* eps     = (const float*)d_in[1];  // (S, B, D)
    const float* W1      = (const float*)d_in[2];  // (H, D)
    const float* Wc      = (const float*)d_in[3];  // (H, CTX)
    const float* b1      = (const float*)d_in[4];  // (H,)
    const float* W2      = (const float*)d_in[5];  // (2D, H)
    const float* b2      = (const float*)d_in[6];  // (2D,)
    float* out = (float*)d_out;

    const size_t need = ((size_t)B_ * H_ + (size_t)D_ * H_ * 2) * sizeof(float);

    if (ws_size >= need) {
        float*  ctx_term = (float*)d_ws;
        float2* WC       = (float2*)(ctx_term + (size_t)B_ * H_);
        ctx_kernel<<<B_, H_, 0, stream>>>(context, Wc, b1, ctx_term);
        pack_kernel<<<(D_ * H_ + 255) / 256, 256, 0, stream>>>(W1, W2, WC);
        const int nwaves = (S_ * B_) / 2;            // 1024 waves, 2 chains each
        ar2_kernel<<<(nwaves * 64) / 256, 256, 0, stream>>>(eps, WC, b2, ctx_term, out);
    } else {
        const int nwaves = S_ * B_;
        ar_fallback_kernel<<<(nwaves * 64) / 256, 256, 0, stream>>>(
            eps, W2, b2, context, Wc, b1, W1, out);
    }
}

// Round 3
// 102.050 us; speedup vs baseline: 1.4131x; 1.0005x over previous
//
#include <hip/hip_runtime.h>
#include <math.h>

// Problem sizes (fixed by setup_inputs): S=2, B=1024, D=128, H=512, CTX=128
constexpr int S_   = 2;
constexpr int B_   = 1024;
constexpr int D_   = 128;
constexpr int H_   = 512;
constexpr int CTX_ = 128;

// Degree-sorted unit permutation (closed form):
//   u < 508: h(u) = (u>>2) + 127*(u&3), degree g(u) = (u>>2)+1
//   u >= 508: h(u) = u,                 degree g(u) = u-507   (degrees 1..4)
// Unit u lives at register slot (u>>6), lane (u&63).
// Step d (1..127) graduates u in [4(d-1), 4d) -> slot (d-1)>>4, lanes 4t..4t+3
// where t=(d-1)&15; plus (for d<=4) extra unit u=507+d at slot 7, lane 60+(d-1).
__device__ __forceinline__ int h_of_u(int u) {
    return (u < 508) ? ((u >> 2) + 127 * (u & 3)) : u;
}
__device__ __forceinline__ int g_of_u(int u) {
    return (u < 508) ? ((u >> 2) + 1) : (u - 507);
}

__device__ __forceinline__ float rlane(float v, int l) {
    return __int_as_float(__builtin_amdgcn_readlane(__float_as_int(v), l));
}
__device__ __forceinline__ float softplus_fast(float x) {
    return fmaxf(x, 0.f) + __logf(1.f + __expf(-fabsf(x)));
}

// ---------------------------------------------------------------------------
// Prep 1: permuted ctx term: ctxp[b][u] = sum_c context[b,c]*Wc[h(u),c] + b1[h(u)]
// ---------------------------------------------------------------------------
__global__ __launch_bounds__(H_) void ctxp_kernel(
    const float* __restrict__ context, const float* __restrict__ Wc,
    const float* __restrict__ b1, float* __restrict__ ctxp)
{
    __shared__ float crow[CTX_];
    const int b = blockIdx.x;
    const int u = threadIdx.x;
    if (u < CTX_) crow[u] = context[(size_t)b * CTX_ + u];
    __syncthreads();
    const int h = h_of_u(u);
    const float* wr = Wc + (size_t)h * CTX_;
    float acc = b1[h];
#pragma unroll
    for (int c = 0; c < CTX_; c += 4) {
        float4 w = *reinterpret_cast<const float4*>(wr + c);
        acc = fmaf(w.x, crow[c + 0], acc);
        acc = fmaf(w.y, crow[c + 1], acc);
        acc = fmaf(w.z, crow[c + 2], acc);
        acc = fmaf(w.w, crow[c + 3], acc);
    }
    ctxp[(size_t)b * H_ + u] = acc;
}

// ---------------------------------------------------------------------------
// Prep 2: pack all step weights.
//  Wp4  [128][4][128] float4 : Wp4[(d*4+c)*128+L][i] = W2[row(c,L)][h(4(d-1)+i)]
//        row(c,L): c=0 -> L (mu,lo), c=1 -> 128+L (ps,lo), c=2 -> 64+L (mu,hi),
//                  c=3 -> 192+L (ps,hi).  d=0 row zeroed.
//  W1p4 [128][2][128] float4 : W1p4[(d*2+half)*128+L][i] =
//        (g(u)>d) ? W1[h(u)][d] : 0,  u=(half*4+i)*64+L   (pre-masked update wts)
//  Wpx4 [4][128]      float4 : extra units u=508+t:
//        Wpx4[t*128+L] = (W2[L][u], W2[128+L][u], W2[64+L][u], W2[192+L][u])
// ---------------------------------------------------------------------------
constexpr int NWP4  = 128 * 4 * 128;   // 65536
constexpr int NW1P4 = 128 * 2 * 128;   // 32768
constexpr int NWPX4 = 4 * 128;         // 512
constexpr int NPACK = NWP4 + NW1P4 + NWPX4;

__global__ __launch_bounds__(256) void pack_kernel(
    const float* __restrict__ W1, const float* __restrict__ W2,
    float4* __restrict__ Wp4, float4* __restrict__ W1p4, float4* __restrict__ Wpx4)
{
    int idx = blockIdx.x * 256 + threadIdx.x;
    if (idx >= NPACK) return;
    if (idx < NWP4) {
        int d = idx >> 9;            // /(4*128)
        int r = idx & 511;
        int c = r >> 7;
        int L = r & 127;
        float4 v = make_float4(0.f, 0.f, 0.f, 0.f);
        if (d > 0) {
            int row = ((c & 1) << 7) + ((c >> 1) << 6) + L;
            int ub = 4 * (d - 1);
            v.x = W2[(size_t)row * H_ + h_of_u(ub + 0)];
            v.y = W2[(size_t)row * H_ + h_of_u(ub + 1)];
            v.z = W2[(size_t)row * H_ + h_of_u(ub + 2)];
            v.w = W2[(size_t)row * H_ + h_of_u(ub + 3)];
        }
        Wp4[idx] = v;
    } else if (idx < NWP4 + NW1P4) {
        int k = idx - NWP4;
        int d = k >> 8;              // /(2*128)
        int r = k & 255;
        int half = r >> 7;
        int L = r & 127;
        float4 v;
        float* vv = &v.x;
#pragma unroll
        for (int i = 0; i < 4; ++i) {
            int u = (half * 4 + i) * 64 + L;
            vv[i] = (g_of_u(u) > d) ? W1[(size_t)h_of_u(u) * D_ + d] : 0.f;
        }
        W1p4[k] = v;
    } else {
        int k = idx - NWP4 - NW1P4;
        int t = k >> 7;
        int L = k & 127;
        int u = 508 + t;             // h(u) = u
        float4 v;
        v.x = W2[(size_t)(L)       * H_ + u];
        v.y = W2[(size_t)(128 + L) * H_ + u];
        v.z = W2[(size_t)(64 + L)  * H_ + u];
        v.w = W2[(size_t)(192 + L) * H_ + u];
        Wpx4[k] = v;
    }
}

// ---------------------------------------------------------------------------
// Main: one wave per chain. Lane L owns units u=s*64+L (slots s=0..7, a[8]) and
// output dims d'=L (acc0/acc1 = mu/ps) and d'=64+L (acc2/acc3).
// Per step d: graduate 4 units (relu once, readlane-broadcast, push into all
// accumulators), read out z_d from the owning lane, rank-1 update pending a[].
// No 64-lane reduction anywhere.
// ---------------------------------------------------------------------------
__global__ __launch_bounds__(256) void ar3_kernel(
    const float* __restrict__ eps, const float4* __restrict__ Wp4,
    const float4* __restrict__ W1p4, const float4* __restrict__ Wpx4,
    const float* __restrict__ b2, const float* __restrict__ ctxp,
    float* __restrict__ out)
{
    const int wv = (int)((blockIdx.x * blockDim.x + threadIdx.x) >> 6);  // chain
    const int L  = (int)(threadIdx.x & 63);
    if (wv >= S_ * B_) return;
    const int b = wv & (B_ - 1);

    float a[8];
#pragma unroll
    for (int s = 0; s < 8; ++s) a[s] = ctxp[(size_t)b * H_ + s * 64 + L];

    float acc0 = b2[L];         // mu, d'=L
    float acc1 = b2[128 + L];   // ps, d'=L
    float acc2 = b2[64 + L];    // mu, d'=64+L
    float acc3 = b2[192 + L];   // ps, d'=64+L

    const float* ep = eps + (size_t)wv * D_;
    float zlo = 0.f, zhi = 0.f;

    // ---- step 0: no graduated units; out[0] = b2 only
    {
        float4 u01 = W1p4[L];
        float4 u23 = W1p4[128 + L];
        float e = ep[0];
        float z = fmaf(softplus_fast(acc1), e, acc0);
        float zb = rlane(z, 0);
        zlo = (L == 0) ? zb : zlo;
        a[0] = fmaf(u01.x, zb, a[0]); a[1] = fmaf(u01.y, zb, a[1]);
        a[2] = fmaf(u01.z, zb, a[2]); a[3] = fmaf(u01.w, zb, a[3]);
        a[4] = fmaf(u23.x, zb, a[4]); a[5] = fmaf(u23.y, zb, a[5]);
        a[6] = fmaf(u23.z, zb, a[6]); a[7] = fmaf(u23.w, zb, a[7]);
    }

#pragma unroll
    for (int p = 0; p < 8; ++p) {
        const int NT = (p == 7) ? 15 : 16;
#pragma unroll 4
        for (int t = 0; t < NT; ++t) {
            const int d = (p << 4) + 1 + t;
            // --- loads (addresses depend only on d)
            const float4* wb = Wp4 + (size_t)d * 512 + L;
            float4 w0 = wb[0], w1 = wb[128], w2 = wb[256], w3 = wb[384];
            const float4* ub = W1p4 + (size_t)d * 256 + L;
            float4 u01 = ub[0], u23 = ub[128];
            float e = ep[d];

            // --- graduation: 4 units at slot p, lanes 4t..4t+3
            float v = fmaxf(a[p], 0.f);
            int lb = 4 * t;
            float s0 = rlane(v, lb + 0);
            float s1 = rlane(v, lb + 1);
            float s2 = rlane(v, lb + 2);
            float s3 = rlane(v, lb + 3);
            // independent 4-term dot, then one add into the loop-carried acc
            float g0 = fmaf(s0, w0.x, fmaf(s1, w0.y, fmaf(s2, w0.z, s3 * w0.w)));
            float g1 = fmaf(s0, w1.x, fmaf(s1, w1.y, fmaf(s2, w1.z, s3 * w1.w)));
            float g2 = fmaf(s0, w2.x, fmaf(s1, w2.y, fmaf(s2, w2.z, s3 * w2.w)));
            float g3 = fmaf(s0, w3.x, fmaf(s1, w3.y, fmaf(s2, w3.z, s3 * w3.w)));
            acc0 += g0; acc1 += g1; acc2 += g2; acc3 += g3;

            if (p == 0 && t < 4) {  // extra low-degree unit at slot 7, lane 60+t
                float v7 = fmaxf(a[7], 0.f);
                float sx = rlane(v7, 60 + t);
                float4 wx = Wpx4[t * 128 + L];
                acc0 = fmaf(sx, wx.x, acc0);
                acc1 = fmaf(sx, wx.y, acc1);
                acc2 = fmaf(sx, wx.z, acc2);
                acc3 = fmaf(sx, wx.w, acc3);
            }

            // --- read out z_d
            bool hi = (d >= 64);
            float mu = hi ? acc2 : acc0;
            float pv = hi ? acc3 : acc1;
            float z = fmaf(softplus_fast(pv), e, mu);
            float zb = rlane(z, d & 63);
            bool mine = (L == (d & 63));
            if (!hi) zlo = mine ? zb : zlo;
            else     zhi = mine ? zb : zhi;

            // --- rank-1 update of pending units (W1p pre-masked)
            a[0] = fmaf(u01.x, zb, a[0]); a[1] = fmaf(u01.y, zb, a[1]);
            a[2] = fmaf(u01.z, zb, a[2]); a[3] = fmaf(u01.w, zb, a[3]);
            a[4] = fmaf(u23.x, zb, a[4]); a[5] = fmaf(u23.y, zb, a[5]);
            a[6] = fmaf(u23.z, zb, a[6]); a[7] = fmaf(u23.w, zb, a[7]);
        }
    }

    out[(size_t)wv * D_ + L]      = zlo;
    out[(size_t)wv * D_ + 64 + L] = zhi;
}

// ---------------------------------------------------------------------------
// Fallback (ws too small): proven round-0 style kernel, no workspace.
// ---------------------------------------------------------------------------
template <int CTRL>
__device__ __forceinline__ float dpp_add(float x)
{
    int r = __builtin_amdgcn_update_dpp(0, __float_as_int(x), CTRL, 0xF, 0xF, true);
    return x + __int_as_float(r);
}
__device__ __forceinline__ float reduce64(float x)
{
    x = dpp_add<0x111>(x);
    x = dpp_add<0x112>(x);
    x = dpp_add<0x114>(x);
    x = dpp_add<0x118>(x);
    x = dpp_add<0x142>(x);
    x = dpp_add<0x143>(x);
    return __int_as_float(__builtin_amdgcn_readlane(__float_as_int(x), 63));
}

__global__ __launch_bounds__(256) void ar_fallback_kernel(
    const float* __restrict__ eps,
    const float* __restrict__ W2,
    const float* __restrict__ b2,
    const float* __restrict__ context,
    const float* __restrict__ Wc,
    const float* __restrict__ b1,
    const float* __restrict__ W1,
    float* __restrict__ out)
{
    const int wave = (int)((blockIdx.x * blockDim.x + threadIdx.x) >> 6);
    const int lane = (int)(threadIdx.x & 63);
    if (wave >= S_ * B_) return;
    const int b  = wave % B_;
    const int hb = lane * 8;

    int mh[8];
#pragma unroll
    for (int j = 0; j < 8; ++j) mh[j] = ((hb + j) % (D_ - 1)) + 1;

    float a[8];
#pragma unroll
    for (int j = 0; j < 8; ++j) a[j] = b1[hb + j];
    for (int c = 0; c < CTX_; ++c) {
        float cv = context[(size_t)b * CTX_ + c];
#pragma unroll
        for (int j = 0; j < 8; ++j)
            a[j] = fmaf(Wc[(size_t)(hb + j) * CTX_ + c], cv, a[j]);
    }

    const float* epsrow = eps + (size_t)wave * D_;
    float* outrow = out + (size_t)wave * D_;
    float zr0 = 0.f, zr1 = 0.f;

    for (int d = 0; d < D_; ++d) {
        const float* w2mu = W2 + (size_t)d * H_ + hb;
        const float* w2ps = W2 + (size_t)(d + D_) * H_ + hb;
        float4 m0 = *reinterpret_cast<const float4*>(w2mu);
        float4 m1 = *reinterpret_cast<const float4*>(w2mu + 4);
        float4 p0 = *reinterpret_cast<const float4*>(w2ps);
        float4 p1 = *reinterpret_cast<const float4*>(w2ps + 4);
        float wmu[8] = {m0.x, m0.y, m0.z, m0.w, m1.x, m1.y, m1.z, m1.w};
        float wps[8] = {p0.x, p0.y, p0.z, p0.w, p1.x, p1.y, p1.z, p1.w};
        float w1v[8];
#pragma unroll
        for (int j = 0; j < 8; ++j) w1v[j] = W1[(size_t)(hb + j) * D_ + d];
        float eps_d = epsrow[d];

        float mu = 0.f, ps = 0.f;
#pragma unroll
        for (int j = 0; j < 8; ++j) {
            float r = fmaxf(a[j], 0.f);
            r = (mh[j] <= d) ? r : 0.f;
            mu = fmaf(wmu[j], r, mu);
            ps = fmaf(wps[j], r, ps);
        }
        mu = reduce64(mu) + b2[d];
        ps = reduce64(ps) + b2[d + D_];

        float z = fmaf(softplus_fast(ps), eps_d, mu);
#pragma unroll
        for (int j = 0; j < 8; ++j) {
            float w = (mh[j] <= d) ? 0.f : w1v[j];
            a[j] = fmaf(w, z, a[j]);
        }
        bool mine = (lane == (d & 63));
        if (d < 64) zr0 = mine ? z : zr0; else zr1 = mine ? z : zr1;
    }

    outrow[lane]      = zr0;
    outrow[lane + 64] = zr1;
}

// ---------------------------------------------------------------------------
extern "C" void kernel_launch(void* const* d_in, const int* in_sizes, int n_in,
                              void* d_out, int out_size, void* d_ws, size_t ws_size,
                              hipStream_t stream)
{
    const float* context = (const float*)d_in[0];  // (B, CTX)
    const float* eps     = (const float*)d_in[1];  // (S, B, D)
    const float* W1      = (const float*)d_in[2];  // (H, D)
    const float* Wc      = (const float*)d_in[3];  // (H, CTX)
    const float* b1      = (const float*)d_in[4];  // (H,)
    const float* W2      = (const float*)d_in[5];  // (2D, H)
    const float* b2      = (const float*)d_in[6];  // (2D,)
    float* out = (float*)d_out;

    // workspace layout (16B-aligned chunks): Wp4 | W1p4 | Wpx4 | ctxp
    const size_t wp4_f   = (size_t)NWP4 * 4;
    const size_t w1p4_f  = (size_t)NW1P4 * 4;
    const size_t wpx4_f  = (size_t)NWPX4 * 4;
    const size_t ctxp_f  = (size_t)B_ * H_;
    const size_t need = (wp4_f + w1p4_f + wpx4_f + ctxp_f) * sizeof(float);

    if (ws_size >= need) {
        float4* Wp4  = (float4*)d_ws;
        float4* W1p4 = Wp4 + NWP4;
        float4* Wpx4 = W1p4 + NW1P4;
        float*  ctxp = (float*)(Wpx4 + NWPX4);

        pack_kernel<<<(NPACK + 255) / 256, 256, 0, stream>>>(W1, W2, Wp4, W1p4, Wpx4);
        ctxp_kernel<<<B_, H_, 0, stream>>>(context, Wc, b1, ctxp);

        const int nthreads = S_ * B_ * 64;           // 2048 waves, 1 chain each
        ar3_kernel<<<nthreads / 256, 256, 0, stream>>>(
            eps, Wp4, W1p4, Wpx4, b2, ctxp, out);
    } else {
        const int nwaves = S_ * B_;
        ar_fallback_kernel<<<(nwaves * 64) / 256, 256, 0, stream>>>(
            eps, W2, b2, context, Wc, b1, W1, out);
    }
}

// Round 4
// 55.033 us; speedup vs baseline: 2.6204x; 1.8544x over previous
//
#include <hip/hip_runtime.h>
#include <math.h>

// Problem sizes (fixed by setup_inputs): S=2, B=1024, D=128, H=512, CTX=128
constexpr int S_   = 2;
constexpr int B_   = 1024;
constexpr int D_   = 128;
constexpr int H_   = 512;
constexpr int CTX_ = 128;

// Degree-sorted unit permutation (closed form):
//   u < 508: h(u) = (u>>2) + 127*(u&3), degree g(u) = (u>>2)+1
//   u >= 508: h(u) = u,                 degree g(u) = u-507   (degrees 1..4)
// Unit u lives at register slot (u>>6), lane (u&63).
// Step d (1..127) graduates u in [4(d-1), 4d) -> slot (d-1)>>4, lanes 4t..4t+3,
// t=(d-1)&15; plus (d<=4) extra unit u=507+d at slot 7, lane 60+(d-1).
__device__ __forceinline__ int h_of_u(int u) {
    return (u < 508) ? ((u >> 2) + 127 * (u & 3)) : u;
}
__device__ __forceinline__ int g_of_u(int u) {
    return (u < 508) ? ((u >> 2) + 1) : (u - 507);
}
__device__ __forceinline__ float rlaneF(float v, int l) {
    return __int_as_float(__builtin_amdgcn_readlane(__float_as_int(v), l));
}
__device__ __forceinline__ float softplus_fast(float x) {
    return fmaxf(x, 0.f) + __logf(1.f + __expf(-fabsf(x)));
}

typedef unsigned int  uint32x4 __attribute__((ext_vector_type(4)));
typedef unsigned int  uint32x2 __attribute__((ext_vector_type(2)));
typedef _Float16      half8    __attribute__((ext_vector_type(8)));
typedef _Float16      half4v   __attribute__((ext_vector_type(4)));
union U16 { uint32x4 u; half8 h; };
union U8  { uint32x2 u; half4v h; };

// ---------------------------------------------------------------------------
// Workspace layout (fp16 packed weights + fp32 permuted ctx term):
//  Wh  [128][2][64] uint32x4 : step d, j in {0,1}, lane L. 8 halves:
//        j=0: h[0..3] = W2[L][h(4(d-1)+i)]      (acc0 / mu-lo)
//             h[4..7] = W2[128+L][...]          (acc1 / ps-lo)
//        j=1: h[0..3] = W2[64+L][...]           (acc2 / mu-hi)
//             h[4..7] = W2[192+L][...]          (acc3 / ps-hi)   d=0 zeroed
//  W1h [128][64] uint32x4 : h[j] = (g(u)>d)? W1[h(u)][d] : 0, u=j*64+L
//  Wpx [4][64]  uint32x2 : extra units u=508+t: (W2[L][u],W2[128+L][u],
//                           W2[64+L][u],W2[192+L][u])
//  ctxp [1024][512] float : permuted ctx term
// ---------------------------------------------------------------------------
constexpr int N_WH  = 128 * 2 * 64;   // 16384 x 16B
constexpr int N_W1H = 128 * 64;       //  8192 x 16B
constexpr int N_WPX = 4 * 64;         //   256 x 8B
constexpr size_t WS_WH_OFF   = 0;
constexpr size_t WS_W1H_OFF  = (size_t)N_WH * 16;                 // 262144
constexpr size_t WS_WPX_OFF  = WS_W1H_OFF + (size_t)N_W1H * 16;   // 393216
constexpr size_t WS_CTXP_OFF = WS_WPX_OFF + (size_t)N_WPX * 8;    // 395264
constexpr size_t WS_NEED     = WS_CTXP_OFF + (size_t)B_ * H_ * 4; // ~2.4MB

// ---------------------------------------------------------------------------
// Prep 1: ctxp[b][u] = sum_c context[b,c]*Wc[h(u),c] + b1[h(u)]
// 8 batches per block -> Wc L2 traffic 32MB instead of 256MB. ctx reads are
// wave-uniform -> scalar loads.
// ---------------------------------------------------------------------------
__global__ __launch_bounds__(512) void ctxp_kernel(
    const float* __restrict__ context, const float* __restrict__ Wc,
    const float* __restrict__ b1, float* __restrict__ ctxp)
{
    const int b0 = blockIdx.x * 8;
    const int u  = threadIdx.x;
    const int h  = h_of_u(u);
    const float* wr = Wc + (size_t)h * CTX_;
    float bb = b1[h];
    float acc[8];
#pragma unroll
    for (int i = 0; i < 8; ++i) acc[i] = bb;
    for (int c = 0; c < CTX_; c += 4) {
        float4 w = *reinterpret_cast<const float4*>(wr + c);
#pragma unroll
        for (int i = 0; i < 8; ++i) {
            const float* cr = context + (size_t)(b0 + i) * CTX_ + c;
            acc[i] = fmaf(w.x, cr[0], fmaf(w.y, cr[1],
                     fmaf(w.z, cr[2], fmaf(w.w, cr[3], acc[i]))));
        }
    }
#pragma unroll
    for (int i = 0; i < 8; ++i)
        ctxp[(size_t)(b0 + i) * H_ + u] = acc[i];
}

// ---------------------------------------------------------------------------
// Prep 2: fp16 weight packing (one 8B/16B output per thread)
// ---------------------------------------------------------------------------
__global__ __launch_bounds__(256) void packh_kernel(
    const float* __restrict__ W1, const float* __restrict__ W2,
    uint32x4* __restrict__ Wh, uint32x4* __restrict__ W1h,
    uint32x2* __restrict__ Wpx)
{
    int idx = blockIdx.x * 256 + threadIdx.x;
    if (idx < N_WH) {
        int d = idx >> 7, r = idx & 127, j = r >> 6, L = r & 63;
        U16 o;
        if (d == 0) {
            o.u = (uint32x4){0u, 0u, 0u, 0u};
        } else {
            int rowA = (j == 0) ? L : (64 + L);
            int rowB = (j == 0) ? (128 + L) : (192 + L);
#pragma unroll
            for (int i = 0; i < 4; ++i) {
                int hu = h_of_u(4 * (d - 1) + i);
                o.h[i]     = (_Float16)W2[(size_t)rowA * H_ + hu];
                o.h[4 + i] = (_Float16)W2[(size_t)rowB * H_ + hu];
            }
        }
        Wh[idx] = o.u;
    } else if (idx < N_WH + N_W1H) {
        int k = idx - N_WH, d = k >> 6, L = k & 63;
        U16 o;
#pragma unroll
        for (int j = 0; j < 8; ++j) {
            int u = j * 64 + L;
            o.h[j] = (g_of_u(u) > d) ? (_Float16)W1[(size_t)h_of_u(u) * D_ + d]
                                     : (_Float16)0.f;
        }
        W1h[k] = o.u;
    } else if (idx < N_WH + N_W1H + N_WPX) {
        int k = idx - N_WH - N_W1H, t = k >> 6, L = k & 63, u = 508 + t;
        U8 o;
        o.h[0] = (_Float16)W2[(size_t)L * H_ + u];
        o.h[1] = (_Float16)W2[(size_t)(128 + L) * H_ + u];
        o.h[2] = (_Float16)W2[(size_t)(64 + L) * H_ + u];
        o.h[3] = (_Float16)W2[(size_t)(192 + L) * H_ + u];
        Wpx[k] = o.u;
    }
}

// ---------------------------------------------------------------------------
// Main kernel: one wave runs the (s=0,b) and (s=1,b) chains (shared weights,
// shared ctx init). fp16 weights via fma-mix (fp32 accumulate). 2-deep A/B
// register prefetch of the weight stream.
// ---------------------------------------------------------------------------
#define AR_STEP(P, dd, tl, SA, SB, SU, WX) do {                               \
    const int d_ = (dd);                                                      \
    float v0_ = fmaxf(a0[(P)], 0.f), v1_ = fmaxf(a1[(P)], 0.f);               \
    const int lb_ = 4 * (tl);                                                 \
    float s00_ = rlaneF(v0_, lb_ + 0), s01_ = rlaneF(v0_, lb_ + 1);           \
    float s02_ = rlaneF(v0_, lb_ + 2), s03_ = rlaneF(v0_, lb_ + 3);           \
    float s10_ = rlaneF(v1_, lb_ + 0), s11_ = rlaneF(v1_, lb_ + 1);           \
    float s12_ = rlaneF(v1_, lb_ + 2), s13_ = rlaneF(v1_, lb_ + 3);           \
    acc00 = fmaf((float)SA.h[0], s00_, acc00);                                \
    acc00 = fmaf((float)SA.h[1], s01_, acc00);                                \
    acc00 = fmaf((float)SA.h[2], s02_, acc00);                                \
    acc00 = fmaf((float)SA.h[3], s03_, acc00);                                \
    acc01 = fmaf((float)SA.h[4], s00_, acc01);                                \
    acc01 = fmaf((float)SA.h[5], s01_, acc01);                                \
    acc01 = fmaf((float)SA.h[6], s02_, acc01);                                \
    acc01 = fmaf((float)SA.h[7], s03_, acc01);                                \
    acc02 = fmaf((float)SB.h[0], s00_, acc02);                                \
    acc02 = fmaf((float)SB.h[1], s01_, acc02);                                \
    acc02 = fmaf((float)SB.h[2], s02_, acc02);                                \
    acc02 = fmaf((float)SB.h[3], s03_, acc02);                                \
    acc03 = fmaf((float)SB.h[4], s00_, acc03);                                \
    acc03 = fmaf((float)SB.h[5], s01_, acc03);                                \
    acc03 = fmaf((float)SB.h[6], s02_, acc03);                                \
    acc03 = fmaf((float)SB.h[7], s03_, acc03);                                \
    acc10 = fmaf((float)SA.h[0], s10_, acc10);                                \
    acc10 = fmaf((float)SA.h[1], s11_, acc10);                                \
    acc10 = fmaf((float)SA.h[2], s12_, acc10);                                \
    acc10 = fmaf((float)SA.h[3], s13_, acc10);                                \
    acc11 = fmaf((float)SA.h[4], s10_, acc11);                                \
    acc11 = fmaf((float)SA.h[5], s11_, acc11);                                \
    acc11 = fmaf((float)SA.h[6], s12_, acc11);                                \
    acc11 = fmaf((float)SA.h[7], s13_, acc11);                                \
    acc12 = fmaf((float)SB.h[0], s10_, acc12);                                \
    acc12 = fmaf((float)SB.h[1], s11_, acc12);                                \
    acc12 = fmaf((float)SB.h[2], s12_, acc12);                                \
    acc12 = fmaf((float)SB.h[3], s13_, acc12);                                \
    acc13 = fmaf((float)SB.h[4], s10_, acc13);                                \
    acc13 = fmaf((float)SB.h[5], s11_, acc13);                                \
    acc13 = fmaf((float)SB.h[6], s12_, acc13);                                \
    acc13 = fmaf((float)SB.h[7], s13_, acc13);                                \
    if ((P) == 0 && d_ <= 4) {                                                \
        float v7a_ = fmaxf(a0[7], 0.f), v7b_ = fmaxf(a1[7], 0.f);             \
        float sx0_ = rlaneF(v7a_, 59 + d_), sx1_ = rlaneF(v7b_, 59 + d_);     \
        acc00 = fmaf((float)WX.h[0], sx0_, acc00);                            \
        acc01 = fmaf((float)WX.h[1], sx0_, acc01);                            \
        acc02 = fmaf((float)WX.h[2], sx0_, acc02);                            \
        acc03 = fmaf((float)WX.h[3], sx0_, acc03);                            \
        acc10 = fmaf((float)WX.h[0], sx1_, acc10);                            \
        acc11 = fmaf((float)WX.h[1], sx1_, acc11);                            \
        acc12 = fmaf((float)WX.h[2], sx1_, acc12);                            \
        acc13 = fmaf((float)WX.h[3], sx1_, acc13);                            \
        int tn_ = d_ + 1; if (tn_ > 3) tn_ = 3;                               \
        WX.u = Wpx2[tn_ * 64 + L];                                            \
    }                                                                         \
    bool lo_ = ((P) < 3) || ((P) == 3 && d_ < 64);                            \
    float e0_ = rlaneF(lo_ ? e0L : e0H, d_ & 63);                             \
    float e1_ = rlaneF(lo_ ? e1L : e1H, d_ & 63);                             \
    float mu0_ = lo_ ? acc00 : acc02, pv0_ = lo_ ? acc01 : acc03;             \
    float mu1_ = lo_ ? acc10 : acc12, pv1_ = lo_ ? acc11 : acc13;             \
    float z0_ = fmaf(softplus_fast(pv0_), e0_, mu0_);                         \
    float z1_ = fmaf(softplus_fast(pv1_), e1_, mu1_);                         \
    float zb0_ = rlaneF(z0_, d_ & 63), zb1_ = rlaneF(z1_, d_ & 63);           \
    bool mine_ = (L == (d_ & 63));                                            \
    z00 = (lo_ && mine_) ? zb0_ : z00;                                        \
    z01 = (!lo_ && mine_) ? zb0_ : z01;                                       \
    z10 = (lo_ && mine_) ? zb1_ : z10;                                        \
    z11 = (!lo_ && mine_) ? zb1_ : z11;                                       \
    a0[0] = fmaf((float)SU.h[0], zb0_, a0[0]);                                \
    a0[1] = fmaf((float)SU.h[1], zb0_, a0[1]);                                \
    a0[2] = fmaf((float)SU.h[2], zb0_, a0[2]);                                \
    a0[3] = fmaf((float)SU.h[3], zb0_, a0[3]);                                \
    a0[4] = fmaf((float)SU.h[4], zb0_, a0[4]);                                \
    a0[5] = fmaf((float)SU.h[5], zb0_, a0[5]);                                \
    a0[6] = fmaf((float)SU.h[6], zb0_, a0[6]);                                \
    a0[7] = fmaf((float)SU.h[7], zb0_, a0[7]);                                \
    a1[0] = fmaf((float)SU.h[0], zb1_, a1[0]);                                \
    a1[1] = fmaf((float)SU.h[1], zb1_, a1[1]);                                \
    a1[2] = fmaf((float)SU.h[2], zb1_, a1[2]);                                \
    a1[3] = fmaf((float)SU.h[3], zb1_, a1[3]);                                \
    a1[4] = fmaf((float)SU.h[4], zb1_, a1[4]);                                \
    a1[5] = fmaf((float)SU.h[5], zb1_, a1[5]);                                \
    a1[6] = fmaf((float)SU.h[6], zb1_, a1[6]);                                \
    a1[7] = fmaf((float)SU.h[7], zb1_, a1[7]);                                \
    int dn_ = d_ + 2; if (dn_ > 127) dn_ = 127;                               \
    SA.u = Wh4[(dn_ * 2 + 0) * 64 + L];                                       \
    SB.u = Wh4[(dn_ * 2 + 1) * 64 + L];                                       \
    SU.u = W1h4[dn_ * 64 + L];                                                \
} while (0)

__global__ __launch_bounds__(256) void ar5_kernel(
    const float* __restrict__ eps, const uint32x4* __restrict__ Wh4,
    const uint32x4* __restrict__ W1h4, const uint32x2* __restrict__ Wpx2,
    const float* __restrict__ b2, const float* __restrict__ ctxp,
    float* __restrict__ out)
{
    const int b = (int)((blockIdx.x * blockDim.x + threadIdx.x) >> 6); // pair id
    const int L = (int)(threadIdx.x & 63);
    if (b >= B_) return;

    // hidden pre-activations for both chains (identical init: same b)
    float a0[8], a1[8];
#pragma unroll
    for (int s = 0; s < 8; ++s) {
        float v = ctxp[(size_t)b * H_ + s * 64 + L];
        a0[s] = v; a1[s] = v;
    }
    // output accumulators (mu-lo, ps-lo, mu-hi, ps-hi) per chain
    float acc00 = b2[L],       acc01 = b2[128 + L];
    float acc02 = b2[64 + L],  acc03 = b2[192 + L];
    float acc10 = acc00, acc11 = acc01, acc12 = acc02, acc13 = acc03;

    const float* ep0 = eps + (size_t)b * D_;          // chain (s=0,b)
    const float* ep1 = eps + (size_t)(B_ + b) * D_;   // chain (s=1,b)
    float e0L = ep0[L], e0H = ep0[64 + L];
    float e1L = ep1[L], e1H = ep1[64 + L];

    float z00 = 0.f, z01 = 0.f, z10 = 0.f, z11 = 0.f;

    // prologue: step-0 update weights + prefetch steps 1,2 + extras 1,2
    U16 u0;  u0.u  = W1h4[0 * 64 + L];
    U16 sA0, sA1, sAu, sB0, sB1, sBu;
    sA0.u = Wh4[(1 * 2 + 0) * 64 + L];
    sA1.u = Wh4[(1 * 2 + 1) * 64 + L];
    sAu.u = W1h4[1 * 64 + L];
    sB0.u = Wh4[(2 * 2 + 0) * 64 + L];
    sB1.u = Wh4[(2 * 2 + 1) * 64 + L];
    sBu.u = W1h4[2 * 64 + L];
    U8 wxA, wxB;
    wxA.u = Wpx2[0 * 64 + L];
    wxB.u = Wpx2[1 * 64 + L];

    // ---- step 0 (no graduated units)
    {
        float e0_ = rlaneF(e0L, 0), e1_ = rlaneF(e1L, 0);
        float z0_ = fmaf(softplus_fast(acc01), e0_, acc00);
        float z1_ = fmaf(softplus_fast(acc11), e1_, acc10);
        float zb0_ = rlaneF(z0_, 0), zb1_ = rlaneF(z1_, 0);
        if (L == 0) { z00 = zb0_; z10 = zb1_; }
#pragma unroll
        for (int j = 0; j < 8; ++j) {
            a0[j] = fmaf((float)u0.h[j], zb0_, a0[j]);
            a1[j] = fmaf((float)u0.h[j], zb1_, a1[j]);
        }
    }

#pragma unroll
    for (int p = 0; p < 8; ++p) {
        const int kmax = (p == 7) ? 7 : 8;
#pragma unroll 1
        for (int k = 0; k < kmax; ++k) {
            const int d1 = 16 * p + 1 + 2 * k;
            AR_STEP(p, d1,     2 * k,     sA0, sA1, sAu, wxA);
            AR_STEP(p, d1 + 1, 2 * k + 1, sB0, sB1, sBu, wxB);
        }
    }
    AR_STEP(7, 127, 14, sA0, sA1, sAu, wxA);

    out[(size_t)b * D_ + L]                  = z00;
    out[(size_t)b * D_ + 64 + L]             = z01;
    out[(size_t)(B_ + b) * D_ + L]           = z10;
    out[(size_t)(B_ + b) * D_ + 64 + L]      = z11;
}

// ---------------------------------------------------------------------------
// Fallback (ws too small): proven round-1 kernel, no workspace.
// ---------------------------------------------------------------------------
template <int CTRL>
__device__ __forceinline__ float dpp_add(float x)
{
    int r = __builtin_amdgcn_update_dpp(0, __float_as_int(x), CTRL, 0xF, 0xF, true);
    return x + __int_as_float(r);
}
__device__ __forceinline__ float reduce64(float x)
{
    x = dpp_add<0x111>(x);
    x = dpp_add<0x112>(x);
    x = dpp_add<0x114>(x);
    x = dpp_add<0x118>(x);
    x = dpp_add<0x142>(x);
    x = dpp_add<0x143>(x);
    return __int_as_float(__builtin_amdgcn_readlane(__float_as_int(x), 63));
}

__global__ __launch_bounds__(256) void ar_fallback_kernel(
    const float* __restrict__ eps,
    const float* __restrict__ W2,
    const float* __restrict__ b2,
    const float* __restrict__ context,
    const float* __restrict__ Wc,
    const float* __restrict__ b1,
    const float* __restrict__ W1,
    float* __restrict__ out)
{
    const int wave = (int)((blockIdx.x * blockDim.x + threadIdx.x) >> 6);
    const int lane = (int)(threadIdx.x & 63);
    if (wave >= S_ * B_) return;
    const int b  = wave % B_;
    const int hb = lane * 8;

    int mh[8];
#pragma unroll
    for (int j = 0; j < 8; ++j) mh[j] = ((hb + j) % (D_ - 1)) + 1;

    float a[8];
#pragma unroll
    for (int j = 0; j < 8; ++j) a[j] = b1[hb + j];
    for (int c = 0; c < CTX_; ++c) {
        float cv = context[(size_t)b * CTX_ + c];
#pragma unroll
        for (int j = 0; j < 8; ++j)
            a[j] = fmaf(Wc[(size_t)(hb + j) * CTX_ + c], cv, a[j]);
    }

    const float* epsrow = eps + (size_t)wave * D_;
    float* outrow = out + (size_t)wave * D_;
    float zr0 = 0.f, zr1 = 0.f;

    for (int d = 0; d < D_; ++d) {
        const float* w2mu = W2 + (size_t)d * H_ + hb;
        const float* w2ps = W2 + (size_t)(d + D_) * H_ + hb;
        float4 m0 = *reinterpret_cast<const float4*>(w2mu);
        float4 m1 = *reinterpret_cast<const float4*>(w2mu + 4);
        float4 p0 = *reinterpret_cast<const float4*>(w2ps);
        float4 p1 = *reinterpret_cast<const float4*>(w2ps + 4);
        float wmu[8] = {m0.x, m0.y, m0.z, m0.w, m1.x, m1.y, m1.z, m1.w};
        float wps[8] = {p0.x, p0.y, p0.z, p0.w, p1.x, p1.y, p1.z, p1.w};
        float w1v[8];
#pragma unroll
        for (int j = 0; j < 8; ++j) w1v[j] = W1[(size_t)(hb + j) * D_ + d];
        float eps_d = epsrow[d];

        float mu = 0.f, ps = 0.f;
#pragma unroll
        for (int j = 0; j < 8; ++j) {
            float r = fmaxf(a[j], 0.f);
            r = (mh[j] <= d) ? r : 0.f;
            mu = fmaf(wmu[j], r, mu);
            ps = fmaf(wps[j], r, ps);
        }
        mu = reduce64(mu) + b2[d];
        ps = reduce64(ps) + b2[d + D_];

        float z = fmaf(softplus_fast(ps), eps_d, mu);
#pragma unroll
        for (int j = 0; j < 8; ++j) {
            float w = (mh[j] <= d) ? 0.f : w1v[j];
            a[j] = fmaf(w, z, a[j]);
        }
        bool mine = (lane == (d & 63));
        if (d < 64) zr0 = mine ? z : zr0; else zr1 = mine ? z : zr1;
    }

    outrow[lane]      = zr0;
    outrow[lane + 64] = zr1;
}

// ---------------------------------------------------------------------------
extern "C" void kernel_launch(void* const* d_in, const int* in_sizes, int n_in,
                              void* d_out, int out_size, void* d_ws, size_t ws_size,
                              hipStream_t stream)
{
    const float* context = (const float*)d_in[0];  // (B, CTX)
    const float* eps     = (const float*)d_in[1];  // (S, B, D)
    const float* W1      = (const float*)d_in[2];  // (H, D)
    const float* Wc      = (const float*)d_in[3];  // (H, CTX)
    const float* b1      = (const float*)d_in[4];  // (H,)
    const float* W2      = (const float*)d_in[5];  // (2D, H)
    const float* b2      = (const float*)d_in[6];  // (2D,)
    float* out = (float*)d_out;

    if (ws_size >= WS_NEED) {
        char* ws = (char*)d_ws;
        uint32x4* Wh   = (uint32x4*)(ws + WS_WH_OFF);
        uint32x4* W1h  = (uint32x4*)(ws + WS_W1H_OFF);
        uint32x2* Wpx  = (uint32x2*)(ws + WS_WPX_OFF);
        float*    ctxp = (float*)(ws + WS_CTXP_OFF);

        const int npack = N_WH + N_W1H + N_WPX;
        packh_kernel<<<(npack + 255) / 256, 256, 0, stream>>>(W1, W2, Wh, W1h, Wpx);
        ctxp_kernel<<<B_ / 8, 512, 0, stream>>>(context, Wc, b1, ctxp);

        // 1024 waves: one wave per batch b, running both s-chains
        ar5_kernel<<<(B_ * 64) / 256, 256, 0, stream>>>(
            eps, Wh, W1h, Wpx, b2, ctxp, out);
    } else {
        const int nwaves = S_ * B_;
        ar_fallback_kernel<<<(nwaves * 64) / 256, 256, 0, stream>>>(
            eps, W2, b2, context, Wc, b1, W1, out);
    }
}